// Round 11
// baseline (57.444 us; speedup 1.0000x reference)
//
#include <hip/hip_runtime.h>

// B=8, N=2048, D=32, H=4, HD=8, BH=32
// ws layout (15MB):
//   q16    [32][2048][8]    f16 (1MB) @ 0     c1*log2e pre-folded
//   kf_ws  [32][128][64][4] f16 (2MB) @ 1MB   K in MFMA-A fragment order
//   vf_ws  [32][128][64][4] f16 (2MB) @ 3MB   V^T in MFMA-B frag order (+ones row d=8)
//   adj16  [64][128][64][8] f16 (8MB) @ 5MB   c2*adj, C-frag order, qt-pair packed
//   attn_ws[8][2048][32]    f32 (2MB) @ 13MB
//
// R11: 4bh x 4qt register batch, 256 blocks (8 bhg x 32 qtg), 8 waves =
// 8 j-splits of 16 jt (denominator complete in-block -> no partial-softmax
// hazard). L2 traffic 192MB (KV x32=128 + adj x8=64) vs R10's 256MB.
// qkv+prep fused into one launch; c1 folded into q16 at fp32.

typedef _Float16 f16;
typedef _Float16 f16x4 __attribute__((ext_vector_type(4)));
typedef _Float16 f16x8 __attribute__((ext_vector_type(8)));
typedef __fp16 h16x2 __attribute__((ext_vector_type(2)));
typedef float f32x4 __attribute__((ext_vector_type(4)));

// Fused: blocks [0,2048) swizzle adj (+ constant-lane fill); [2048,3072) qkv.
__global__ __launch_bounds__(256) void prep_qkv_kernel(
    const float* __restrict__ x, const float* __restrict__ Wqkv,
    const float* __restrict__ bqkv, const float* __restrict__ adj,
    const float* __restrict__ gw_p, f16* __restrict__ q16,
    f16* __restrict__ kf_ws, f16* __restrict__ vf_ws,
    f16* __restrict__ adj16) {
  const float LOG2E = 1.4426950408889634f;
  float blend = 1.f / (1.f + __expf(-gw_p[0]));
  int tid = threadIdx.x;
  __shared__ float Ws[32 * 96];
  __shared__ float bsh[96];
  __shared__ float xs[16 * 32];

  if (blockIdx.x < 2048) {
    float c2 = blend * 5.f * LOG2E;
    int gid = blockIdx.x * 256 + tid;          // 8192 tiles * 64 lanes
    int tile = gid >> 6, lane = gid & 63;
    int qtp = tile >> 7, jt = tile & 127;
    int col = jt * 16 + (lane >> 4) * 4;
    f32x4 v0 = *(const f32x4*)(adj + (size_t)(qtp * 32 + (lane & 15)) * 2048 + col);
    f32x4 v1 = *(const f32x4*)(adj + (size_t)(qtp * 32 + 16 + (lane & 15)) * 2048 + col);
    f16x8 r;
    r[0] = (f16)(c2 * v0[0]); r[1] = (f16)(c2 * v0[1]);
    r[2] = (f16)(c2 * v0[2]); r[3] = (f16)(c2 * v0[3]);
    r[4] = (f16)(c2 * v1[0]); r[5] = (f16)(c2 * v1[1]);
    r[6] = (f16)(c2 * v1[2]); r[7] = (f16)(c2 * v1[3]);
    *(f16x8*)(adj16 + (size_t)gid * 8) = r;
    if (gid < 262144) {  // 4096 k/v fragment tiles: constant lanes
      const f16x4 z = {};
      if (lane >= 32) *(f16x4*)(kf_ws + (size_t)gid * 4) = z;
      int dq = lane & 15;
      if (dq == 8) {
        f16x4 ones = {(f16)1.f, (f16)1.f, (f16)1.f, (f16)1.f};
        *(f16x4*)(vf_ws + (size_t)gid * 4) = ones;
      } else if (dq > 8) {
        *(f16x4*)(vf_ws + (size_t)gid * 4) = z;
      }
    }
  } else {
    float c1 = (1.f - blend) * 0.35355339059327373f * LOG2E;
    int blk = blockIdx.x - 2048;
    for (int i = tid; i < 32 * 96; i += 256) Ws[i] = Wqkv[i];
    if (tid < 96) bsh[tid] = bqkv[tid];
    int rowbase = blk * 16;
    for (int i = tid; i < 16 * 32; i += 256) xs[i] = x[rowbase * 32 + i];
    __syncthreads();
#pragma unroll
    for (int e = 0; e < 6; ++e) {
      int idx = tid + e * 256;
      int r = idx / 96, c = idx % 96;
      float acc = bsh[c];
#pragma unroll
      for (int k = 0; k < 32; ++k) acc += xs[r * 32 + k] * Ws[k * 96 + c];
      int nrow = rowbase + r;
      int b = nrow >> 11, n = nrow & 2047;
      int s = c >> 5, h = (c >> 3) & 3, d = c & 7;
      int bh = b * 4 + h;
      int jt = n >> 4, jr = n & 15;
      if (s == 0) {
        q16[((size_t)bh * 2048 + n) * 8 + d] = (f16)(acc * c1);
      } else if (s == 1) {
        int lane = ((d >> 2) << 4) | jr;   // K frag: lane=(d>>2)*16+jr, e=d&3
        kf_ws[(((size_t)bh * 128 + jt) * 64 + lane) * 4 + (d & 3)] = (f16)acc;
      } else {
        int lane = ((jr >> 2) << 4) | d;   // V frag: lane=(jr>>2)*16+d, e=jr&3
        vf_ws[(((size_t)bh * 128 + jt) * 64 + lane) * 4 + (jr & 3)] = (f16)acc;
      }
    }
  }
}

__global__ __launch_bounds__(512, 2) void attn_kernel(
    const f16* __restrict__ q16, const f16* __restrict__ kf_ws,
    const f16* __restrict__ vf_ws, const f16* __restrict__ adj16,
    float* __restrict__ attn_ws) {
  int blk = blockIdx.x;                 // 256 blocks
  int bhg = blk & 7;                    // 8 bh-groups of 4 (fastest: share adj)
  int qtg = blk >> 3;                   // 32 qt-groups of 4
  int tid = threadIdx.x;
  int w = tid >> 6, lane = tid & 63;    // w = j-split (16 jt each)
  int lq = lane & 15, lh = lane >> 4;
  int bh0 = bhg * 4;
  int jt0 = w * 16;

  const f16* kp = kf_ws + (((size_t)bh0 * 128 + jt0) * 64 + lane) * 4;
  const f16* vp = vf_ws + (((size_t)bh0 * 128 + jt0) * 64 + lane) * 4;
  int qtp0 = qtg * 2;
  const f16* ap0 = adj16 + (((size_t)qtp0 * 128 + jt0) * 64 + lane) * 8;
  const f16* ap1 = ap0 + (size_t)128 * 64 * 8;

  // Q fragments (c1 pre-folded in q16): qf[u][m] for bh0+u, qt=qtg*4+m
  f16x4 qf[4][4];
#pragma unroll
  for (int u = 0; u < 4; ++u)
#pragma unroll
    for (int m = 0; m < 4; ++m) {
      f16x4 t = {};
      if (lane < 32)
        t = *(const f16x4*)(q16 + ((size_t)(bh0 + u) * 2048 +
                                   (qtg * 4 + m) * 16 + lq) * 8 + lh * 4);
      qf[u][m] = t;
    }

  f32x4 acc[4][4];
#pragma unroll
  for (int u = 0; u < 4; ++u)
#pragma unroll
    for (int m = 0; m < 4; ++m) acc[u][m] = (f32x4){0.f, 0.f, 0.f, 0.f};
  const f32x4 zero4 = {0.f, 0.f, 0.f, 0.f};

#pragma unroll 2
  for (int t = 0; t < 16; ++t) {
    f16x4 kf[4], vf[4];
#pragma unroll
    for (int u = 0; u < 4; ++u) {
      kf[u] = *(const f16x4*)(kp + u * 32768 + t * 256);
      vf[u] = *(const f16x4*)(vp + u * 32768 + t * 256);
    }
    f16x8 av0 = *(const f16x8*)(ap0 + t * 512);
    f16x8 av1 = *(const f16x8*)(ap1 + t * 512);
#pragma unroll
    for (int u = 0; u < 4; ++u) {
#pragma unroll
      for (int m = 0; m < 4; ++m) {
        f32x4 s = __builtin_amdgcn_mfma_f32_16x16x16f16(kf[u], qf[u][m], zero4, 0, 0, 0);
        float a0 = (float)((m < 2) ? av0[(m & 1) * 4 + 0] : av1[(m & 1) * 4 + 0]);
        float a1 = (float)((m < 2) ? av0[(m & 1) * 4 + 1] : av1[(m & 1) * 4 + 1]);
        float a2 = (float)((m < 2) ? av0[(m & 1) * 4 + 2] : av1[(m & 1) * 4 + 2]);
        float a3 = (float)((m < 2) ? av0[(m & 1) * 4 + 3] : av1[(m & 1) * 4 + 3]);
        float e0 = __builtin_amdgcn_exp2f(s[0] + a0);
        float e1 = __builtin_amdgcn_exp2f(s[1] + a1);
        float e2 = __builtin_amdgcn_exp2f(s[2] + a2);
        float e3 = __builtin_amdgcn_exp2f(s[3] + a3);
        h16x2 p01 = __builtin_amdgcn_cvt_pkrtz(e0, e1);
        h16x2 p23 = __builtin_amdgcn_cvt_pkrtz(e2, e3);
        f16x4 pa;
        pa[0] = (f16)(float)p01[0]; pa[1] = (f16)(float)p01[1];
        pa[2] = (f16)(float)p23[0]; pa[3] = (f16)(float)p23[1];
        acc[u][m] = __builtin_amdgcn_mfma_f32_16x16x16f16(pa, vf[u], acc[u][m], 0, 0, 0);
      }
    }
  }

  // Tree merge of 8 j-split partials (64KB LDS): 8 -> 4 -> 2 -> 1.
  __shared__ f32x4 mlds[4][16][64];
  if (w & 1) {  // waves 1,3,5,7 write slot w>>1
#pragma unroll
    for (int u = 0; u < 4; ++u)
#pragma unroll
      for (int m = 0; m < 4; ++m) mlds[w >> 1][u * 4 + m][lane] = acc[u][m];
  }
  __syncthreads();
  if (!(w & 1)) {  // waves 0,2,4,6 absorb
#pragma unroll
    for (int u = 0; u < 4; ++u)
#pragma unroll
      for (int m = 0; m < 4; ++m) {
        f32x4 o = mlds[w >> 1][u * 4 + m][lane];
        acc[u][m][0] += o[0]; acc[u][m][1] += o[1];
        acc[u][m][2] += o[2]; acc[u][m][3] += o[3];
      }
  }
  __syncthreads();
  if (w == 2 || w == 6) {  // write slots 0,1
#pragma unroll
    for (int u = 0; u < 4; ++u)
#pragma unroll
      for (int m = 0; m < 4; ++m) mlds[(w >> 2)][u * 4 + m][lane] = acc[u][m];
  }
  __syncthreads();
  if (w == 0 || w == 4) {  // absorb slots 0,1
#pragma unroll
    for (int u = 0; u < 4; ++u)
#pragma unroll
      for (int m = 0; m < 4; ++m) {
        f32x4 o = mlds[(w >> 2)][u * 4 + m][lane];
        acc[u][m][0] += o[0]; acc[u][m][1] += o[1];
        acc[u][m][2] += o[2]; acc[u][m][3] += o[3];
      }
  }
  __syncthreads();
  if (w == 4) {  // write slot 2
#pragma unroll
    for (int u = 0; u < 4; ++u)
#pragma unroll
      for (int m = 0; m < 4; ++m) mlds[2][u * 4 + m][lane] = acc[u][m];
  }
  __syncthreads();
  if (w == 0) {
#pragma unroll
    for (int u = 0; u < 4; ++u)
#pragma unroll
      for (int m = 0; m < 4; ++m) {
        f32x4 o = mlds[2][u * 4 + m][lane];
        acc[u][m][0] += o[0]; acc[u][m][1] += o[1];
        acc[u][m][2] += o[2]; acc[u][m][3] += o[3];
      }
    // epilogue: acc(l,r) = out[q=qt*16+lh*4+r][d=lq]; denominator at d=8
    int dsrc = (lane & 48) | 8;
#pragma unroll
    for (int u = 0; u < 4; ++u) {
      int bh = bh0 + u;
      int b = bh >> 2, h = bh & 3;
#pragma unroll
      for (int m = 0; m < 4; ++m) {
        f32x4 s = acc[u][m];
        float d0 = __shfl(s[0], dsrc);
        float d1 = __shfl(s[1], dsrc);
        float d2 = __shfl(s[2], dsrc);
        float d3 = __shfl(s[3], dsrc);
        if (lq < 8) {
          int qt = qtg * 4 + m;
          size_t base = ((size_t)b * 2048 + qt * 16 + lh * 4) * 32 + h * 8 + lq;
          attn_ws[base]      = s[0] / d0;
          attn_ws[base + 32] = s[1] / d1;
          attn_ws[base + 64] = s[2] / d2;
          attn_ws[base + 96] = s[3] / d3;
        }
      }
    }
  }
}

__global__ __launch_bounds__(256) void out_ln_kernel(
    const float* __restrict__ attn_ws, const float* __restrict__ x,
    const float* __restrict__ Wout, const float* __restrict__ bout,
    const float* __restrict__ gamma, const float* __restrict__ beta,
    float* __restrict__ out) {
  __shared__ float Ws[32 * 32];
  __shared__ float bs[32], gs[32], bts[32];
  int tid = threadIdx.x;
  for (int i = tid; i < 1024; i += 256) Ws[i] = Wout[i];
  if (tid < 32) { bs[tid] = bout[tid]; gs[tid] = gamma[tid]; bts[tid] = beta[tid]; }
  __syncthreads();
  int row = blockIdx.x * 8 + (tid >> 5);
  int d = tid & 31;
  const float* ar = attn_ws + (size_t)row * 32;
  float acc = bs[d];
#pragma unroll
  for (int k = 0; k < 32; ++k) acc += ar[k] * Ws[k * 32 + d];
  float res = acc + x[(size_t)row * 32 + d];
  float s1 = res, s2 = res * res;
#pragma unroll
  for (int off = 16; off >= 1; off >>= 1) {
    s1 += __shfl_xor(s1, off);
    s2 += __shfl_xor(s2, off);
  }
  float mu = s1 * 0.03125f;
  float var = s2 * 0.03125f - mu * mu;
  float r = rsqrtf(var + 1e-5f);
  out[(size_t)row * 32 + d] = (res - mu) * r * gs[d] + bts[d];
}

extern "C" void kernel_launch(void* const* d_in, const int* in_sizes, int n_in,
                              void* d_out, int out_size, void* d_ws, size_t ws_size,
                              hipStream_t stream) {
  const float* x     = (const float*)d_in[0];
  const float* adj   = (const float*)d_in[1];
  const float* gw    = (const float*)d_in[2];
  const float* Wqkv  = (const float*)d_in[3];
  const float* bqkv  = (const float*)d_in[4];
  const float* Wout  = (const float*)d_in[5];
  const float* bout  = (const float*)d_in[6];
  const float* gamma = (const float*)d_in[7];
  const float* beta  = (const float*)d_in[8];
  float* out = (float*)d_out;

  char* wsb = (char*)d_ws;
  f16* q16       = (f16*)wsb;                     // 1MB
  f16* kf_ws     = (f16*)(wsb + (1 << 20));       // 2MB
  f16* vf_ws     = (f16*)(wsb + (3 << 20));       // 2MB
  f16* adj16     = (f16*)(wsb + (5 << 20));       // 8MB
  float* attn_ws = (float*)(wsb + (13 << 20));    // 2MB

  prep_qkv_kernel<<<3072, 256, 0, stream>>>(x, Wqkv, bqkv, adj, gw,
                                            q16, kf_ws, vf_ws, adj16);
  attn_kernel<<<256, 512, 0, stream>>>(q16, kf_ws, vf_ws, adj16, attn_ws);
  out_ln_kernel<<<2048, 256, 0, stream>>>(attn_ws, x, Wout, bout, gamma, beta, out);
}

// Round 12
// 47.080 us; speedup vs baseline: 1.2201x; 1.2201x over previous
//
#include <hip/hip_runtime.h>

// B=8, N=2048, D=32, H=4, HD=8, BH=32
// ws layout (15MB):
//   q16    [32][2048][8]    f16 (1MB) @ 0     c1*log2e pre-folded
//   kf_ws  [32][128][64][4] f16 (2MB) @ 1MB   K in MFMA-A fragment order
//   vf_ws  [32][128][64][4] f16 (2MB) @ 3MB   V^T in MFMA-B frag order (+ones row d=8)
//   adj16  [64][128][64][8] f16 (8MB) @ 5MB   exp2(c2*adj), C-frag order, qt-pair packed
//   attn_ws[8][2048][32]    f32 (2MB) @ 13MB
//
// R12 = R10 structure (512 blocks, 2bh x 4qt, 8 j-split waves, parallel
// epilogue) + (1) exp2-prefolded adj consumed via v_pk_mul_f16 (kills
// 4 cvt + 4 add per subtile), (2) XCD-aware block swizzle: each XCD owns a
// 4-qtq chunk so its adj16 slice (1MB) is L2-resident.

typedef _Float16 f16;
typedef _Float16 f16x4 __attribute__((ext_vector_type(4)));
typedef _Float16 f16x8 __attribute__((ext_vector_type(8)));
typedef __fp16 h16x2 __attribute__((ext_vector_type(2)));
typedef __fp16 h16x8 __attribute__((ext_vector_type(8)));
typedef float f32x4 __attribute__((ext_vector_type(4)));

// Fused: blocks [0,2048) swizzle adj (+ constant-lane fill); [2048,3072) qkv.
__global__ __launch_bounds__(256) void prep_qkv_kernel(
    const float* __restrict__ x, const float* __restrict__ Wqkv,
    const float* __restrict__ bqkv, const float* __restrict__ adj,
    const float* __restrict__ gw_p, f16* __restrict__ q16,
    f16* __restrict__ kf_ws, f16* __restrict__ vf_ws,
    f16* __restrict__ adj16) {
  const float LOG2E = 1.4426950408889634f;
  float blend = 1.f / (1.f + __expf(-gw_p[0]));
  int tid = threadIdx.x;
  __shared__ float Ws[32 * 96];
  __shared__ float bsh[96];
  __shared__ float xs[16 * 32];

  if (blockIdx.x < 2048) {
    float c2 = blend * 5.f * LOG2E;
    int gid = blockIdx.x * 256 + tid;          // 8192 tiles * 64 lanes
    int tile = gid >> 6, lane = gid & 63;
    int qtp = tile >> 7, jt = tile & 127;
    int col = jt * 16 + (lane >> 4) * 4;
    f32x4 v0 = *(const f32x4*)(adj + (size_t)(qtp * 32 + (lane & 15)) * 2048 + col);
    f32x4 v1 = *(const f32x4*)(adj + (size_t)(qtp * 32 + 16 + (lane & 15)) * 2048 + col);
    f16x8 r;  // store exp2(c2*adj): consumed multiplicatively in attn
    r[0] = (f16)__builtin_amdgcn_exp2f(c2 * v0[0]);
    r[1] = (f16)__builtin_amdgcn_exp2f(c2 * v0[1]);
    r[2] = (f16)__builtin_amdgcn_exp2f(c2 * v0[2]);
    r[3] = (f16)__builtin_amdgcn_exp2f(c2 * v0[3]);
    r[4] = (f16)__builtin_amdgcn_exp2f(c2 * v1[0]);
    r[5] = (f16)__builtin_amdgcn_exp2f(c2 * v1[1]);
    r[6] = (f16)__builtin_amdgcn_exp2f(c2 * v1[2]);
    r[7] = (f16)__builtin_amdgcn_exp2f(c2 * v1[3]);
    *(f16x8*)(adj16 + (size_t)gid * 8) = r;
    if (gid < 262144) {  // 4096 k/v fragment tiles: constant lanes
      const f16x4 z = {};
      if (lane >= 32) *(f16x4*)(kf_ws + (size_t)gid * 4) = z;
      int dq = lane & 15;
      if (dq == 8) {
        f16x4 ones = {(f16)1.f, (f16)1.f, (f16)1.f, (f16)1.f};
        *(f16x4*)(vf_ws + (size_t)gid * 4) = ones;
      } else if (dq > 8) {
        *(f16x4*)(vf_ws + (size_t)gid * 4) = z;
      }
    }
  } else {
    float c1 = (1.f - blend) * 0.35355339059327373f * LOG2E;
    int blk = blockIdx.x - 2048;
    for (int i = tid; i < 32 * 96; i += 256) Ws[i] = Wqkv[i];
    if (tid < 96) bsh[tid] = bqkv[tid];
    int rowbase = blk * 16;
    for (int i = tid; i < 16 * 32; i += 256) xs[i] = x[rowbase * 32 + i];
    __syncthreads();
#pragma unroll
    for (int e = 0; e < 6; ++e) {
      int idx = tid + e * 256;
      int r = idx / 96, c = idx % 96;
      float acc = bsh[c];
#pragma unroll
      for (int k = 0; k < 32; ++k) acc += xs[r * 32 + k] * Ws[k * 96 + c];
      int nrow = rowbase + r;
      int b = nrow >> 11, n = nrow & 2047;
      int s = c >> 5, h = (c >> 3) & 3, d = c & 7;
      int bh = b * 4 + h;
      int jt = n >> 4, jr = n & 15;
      if (s == 0) {
        q16[((size_t)bh * 2048 + n) * 8 + d] = (f16)(acc * c1);
      } else if (s == 1) {
        int lane = ((d >> 2) << 4) | jr;   // K frag: lane=(d>>2)*16+jr, e=d&3
        kf_ws[(((size_t)bh * 128 + jt) * 64 + lane) * 4 + (d & 3)] = (f16)acc;
      } else {
        int lane = ((jr >> 2) << 4) | d;   // V frag: lane=(jr>>2)*16+d, e=jr&3
        vf_ws[(((size_t)bh * 128 + jt) * 64 + lane) * 4 + (jr & 3)] = (f16)acc;
      }
    }
  }
}

__global__ __launch_bounds__(512, 4) void attn_kernel(
    const f16* __restrict__ q16, const f16* __restrict__ kf_ws,
    const f16* __restrict__ vf_ws, const f16* __restrict__ adj16,
    float* __restrict__ attn_ws) {
  // XCD-aware swizzle: XCD (= blk&7 heuristically) owns a 4-qtq chunk, so
  // its adj16 slice (8 qt-pairs * 128KB = 1MB) stays L2-resident.
  int blk = blockIdx.x;                 // 512 blocks
  int chunk = blk & 7;
  int within = blk >> 3;                // 0..63
  int bhp = within & 15;                // 16 bh-pairs (adj-sharing, same XCD)
  int qtq = (chunk << 2) | (within >> 4);  // 32 qt-quads
  int tid = threadIdx.x;
  int w = tid >> 6, lane = tid & 63;    // w = j-split (16 jt each)
  int lq = lane & 15, lh = lane >> 4;
  int bh0 = bhp * 2;
  int jt0 = w * 16;

  const f16* kp0 = kf_ws + (((size_t)bh0 * 128 + jt0) * 64 + lane) * 4;
  const f16* kp1 = kp0 + (size_t)128 * 64 * 4;              // bh0+1
  const f16* vp0 = vf_ws + (((size_t)bh0 * 128 + jt0) * 64 + lane) * 4;
  const f16* vp1 = vp0 + (size_t)128 * 64 * 4;
  const f16* ap0 = adj16 + (((size_t)(qtq * 2) * 128 + jt0) * 64 + lane) * 8;
  const f16* ap1 = ap0 + (size_t)128 * 64 * 8;              // qt-pair +1

  // Q fragments (c1 pre-folded in q16): qf[u][m] for bh=bh0+u, qt=qtq*4+m
  f16x4 qf[2][4];
#pragma unroll
  for (int u = 0; u < 2; ++u)
#pragma unroll
    for (int m = 0; m < 4; ++m) {
      f16x4 t = {};
      if (lane < 32)
        t = *(const f16x4*)(q16 + ((size_t)(bh0 + u) * 2048 +
                                   (qtq * 4 + m) * 16 + lq) * 8 + lh * 4);
      qf[u][m] = t;
    }

  f32x4 acc[2][4];
#pragma unroll
  for (int u = 0; u < 2; ++u)
#pragma unroll
    for (int m = 0; m < 4; ++m) acc[u][m] = (f32x4){0.f, 0.f, 0.f, 0.f};
  const f32x4 zero4 = {0.f, 0.f, 0.f, 0.f};

#pragma unroll 4
  for (int t = 0; t < 16; ++t) {
    f16x4 kf0 = *(const f16x4*)(kp0 + t * 256);
    f16x4 kf1 = *(const f16x4*)(kp1 + t * 256);
    f16x4 vf0 = *(const f16x4*)(vp0 + t * 256);
    f16x4 vf1 = *(const f16x4*)(vp1 + t * 256);
    h16x8 av0 = *(const h16x8*)(ap0 + t * 512);
    h16x8 av1 = *(const h16x8*)(ap1 + t * 512);
#pragma unroll
    for (int u = 0; u < 2; ++u) {
      f16x4 kfu = u ? kf1 : kf0;
      f16x4 vfu = u ? vf1 : vf0;
#pragma unroll
      for (int m = 0; m < 4; ++m) {
        f32x4 s = __builtin_amdgcn_mfma_f32_16x16x16f16(kfu, qf[u][m], zero4, 0, 0, 0);
        h16x8 av = (m < 2) ? av0 : av1;
        int b4 = (m & 1) * 4;
        float e0 = __builtin_amdgcn_exp2f(s[0]);
        float e1 = __builtin_amdgcn_exp2f(s[1]);
        float e2 = __builtin_amdgcn_exp2f(s[2]);
        float e3 = __builtin_amdgcn_exp2f(s[3]);
        h16x2 p01 = __builtin_amdgcn_cvt_pkrtz(e0, e1);
        h16x2 p23 = __builtin_amdgcn_cvt_pkrtz(e2, e3);
        h16x2 ea01 = {av[b4 + 0], av[b4 + 1]};
        h16x2 ea23 = {av[b4 + 2], av[b4 + 3]};
        p01 *= ea01;   // v_pk_mul_f16: p = exp2(s) * exp2(c2*adj)
        p23 *= ea23;
        f16x4 pa;
        pa[0] = (f16)(float)p01[0]; pa[1] = (f16)(float)p01[1];
        pa[2] = (f16)(float)p23[0]; pa[3] = (f16)(float)p23[1];
        acc[u][m] = __builtin_amdgcn_mfma_f32_16x16x16f16(pa, vfu, acc[u][m], 0, 0, 0);
      }
    }
  }

  // merge 8 j-split partials; parallel epilogue: wave w reduces slot p=w.
  __shared__ f32x4 mlds[8][8][64];  // 64KB
#pragma unroll
  for (int u = 0; u < 2; ++u)
#pragma unroll
    for (int m = 0; m < 4; ++m) mlds[w][u * 4 + m][lane] = acc[u][m];
  __syncthreads();
  int p = w;
  f32x4 sum = mlds[0][p][lane];
#pragma unroll
  for (int s = 1; s < 8; ++s) {
    f32x4 o = mlds[s][p][lane];
    sum[0] += o[0]; sum[1] += o[1]; sum[2] += o[2]; sum[3] += o[3];
  }
  // sum(l,r) = out[q = qt*16 + lh*4 + r][d = lq]; denominator at d=8
  int dsrc = (lane & 48) | 8;
  float d0 = __shfl(sum[0], dsrc);
  float d1 = __shfl(sum[1], dsrc);
  float d2 = __shfl(sum[2], dsrc);
  float d3 = __shfl(sum[3], dsrc);
  if (lq < 8) {
    int bh = bh0 + (p >> 2);
    int b = bh >> 2, h = bh & 3;
    int qt0 = (qtq * 4 + (p & 3)) * 16;
    size_t base = ((size_t)b * 2048 + qt0 + lh * 4) * 32 + h * 8 + lq;
    attn_ws[base]      = sum[0] / d0;
    attn_ws[base + 32] = sum[1] / d1;
    attn_ws[base + 64] = sum[2] / d2;
    attn_ws[base + 96] = sum[3] / d3;
  }
}

__global__ __launch_bounds__(256) void out_ln_kernel(
    const float* __restrict__ attn_ws, const float* __restrict__ x,
    const float* __restrict__ Wout, const float* __restrict__ bout,
    const float* __restrict__ gamma, const float* __restrict__ beta,
    float* __restrict__ out) {
  __shared__ float Ws[32 * 32];
  __shared__ float bs[32], gs[32], bts[32];
  int tid = threadIdx.x;
  for (int i = tid; i < 1024; i += 256) Ws[i] = Wout[i];
  if (tid < 32) { bs[tid] = bout[tid]; gs[tid] = gamma[tid]; bts[tid] = beta[tid]; }
  __syncthreads();
  int row = blockIdx.x * 8 + (tid >> 5);
  int d = tid & 31;
  const float* ar = attn_ws + (size_t)row * 32;
  float acc = bs[d];
#pragma unroll
  for (int k = 0; k < 32; ++k) acc += ar[k] * Ws[k * 32 + d];
  float res = acc + x[(size_t)row * 32 + d];
  float s1 = res, s2 = res * res;
#pragma unroll
  for (int off = 16; off >= 1; off >>= 1) {
    s1 += __shfl_xor(s1, off);
    s2 += __shfl_xor(s2, off);
  }
  float mu = s1 * 0.03125f;
  float var = s2 * 0.03125f - mu * mu;
  float r = rsqrtf(var + 1e-5f);
  out[(size_t)row * 32 + d] = (res - mu) * r * gs[d] + bts[d];
}

extern "C" void kernel_launch(void* const* d_in, const int* in_sizes, int n_in,
                              void* d_out, int out_size, void* d_ws, size_t ws_size,
                              hipStream_t stream) {
  const float* x     = (const float*)d_in[0];
  const float* adj   = (const float*)d_in[1];
  const float* gw    = (const float*)d_in[2];
  const float* Wqkv  = (const float*)d_in[3];
  const float* bqkv  = (const float*)d_in[4];
  const float* Wout  = (const float*)d_in[5];
  const float* bout  = (const float*)d_in[6];
  const float* gamma = (const float*)d_in[7];
  const float* beta  = (const float*)d_in[8];
  float* out = (float*)d_out;

  char* wsb = (char*)d_ws;
  f16* q16       = (f16*)wsb;                     // 1MB
  f16* kf_ws     = (f16*)(wsb + (1 << 20));       // 2MB
  f16* vf_ws     = (f16*)(wsb + (3 << 20));       // 2MB
  f16* adj16     = (f16*)(wsb + (5 << 20));       // 8MB
  float* attn_ws = (float*)(wsb + (13 << 20));    // 2MB

  prep_qkv_kernel<<<3072, 256, 0, stream>>>(x, Wqkv, bqkv, adj, gw,
                                            q16, kf_ws, vf_ws, adj16);
  attn_kernel<<<512, 512, 0, stream>>>(q16, kf_ws, vf_ws, adj16, attn_ws);
  out_ln_kernel<<<2048, 256, 0, stream>>>(attn_ws, x, Wout, bout, gamma, beta, out);
}